// Round 11
// baseline (325.775 us; speedup 1.0000x reference)
//
#include <hip/hip_runtime.h>

#define NN  100000
#define FIN 165
#define HID 128
#define NBUCK 391        // ceil(NN/256), bucket = dst >> 8
#define CHUNK 2048       // edges per block in bucket passes (small => high occupancy)
#define KPAD 192         // FIN padded to 6 k-steps of 32
#define BH_STRIDE 400    // per-block histogram row stride

typedef __attribute__((ext_vector_type(4))) float f32x4;
typedef __attribute__((ext_vector_type(8))) short short8;

// ws layout (4-byte units). h1 packed uint = bf16 pair (ch, ch+64) per node.
#define OFF_DINV   0
#define OFF_H1     100352
#define OFF_Z      (OFF_H1 + NN * 64)
#define OFF_ROWPTR (OFF_Z + 2 * NN)
#define OFF_GCNT   (OFF_ROWPTR + 100352)
#define OFF_GBASE  (OFF_GCNT + 512)
#define OFF_GCUR   (OFF_GBASE + 512)
#define OFF_BUCK   (OFF_GCUR + 512)
#define OFF_EDATA  (OFF_BUCK + 3200000)
#define OFF_WTHI   (OFF_EDATA + 3200000)          // 128*KPAD ushorts = 12288 uints
#define OFF_WTLO   (OFF_WTHI + 12288)
#define OFF_BHIST  (OFF_WTLO + 12288)             // nchb(1563) * BH_STRIDE ints ~= 625k
// end ~= 14.1M * 4B ~= 57 MB

__device__ __forceinline__ unsigned bf16rne(float f) {
    unsigned u = __float_as_uint(f);
    return (u + 0x7FFFu + ((u >> 16) & 1u)) >> 16;
}

__device__ __forceinline__ float2 bf2_to_f2(unsigned int u) {
    float2 r;
    r.x = __uint_as_float(u << 16);
    r.y = __uint_as_float(u & 0xffff0000u);
    return r;
}

__device__ __forceinline__ short8 ldfrag(const ushort* p) {
    union { uint2 u[2]; short8 s; } f;
    f.u[0] = *(const uint2*)p;          // k = 4g .. 4g+3
    f.u[1] = *(const uint2*)(p + 16);   // k = 16+4g .. 16+4g+3
    return f.s;
}

// split W1 into bf16 hi/lo, transposed to [ch][k] with K zero-padded to KPAD.
// Also zeroes gcnt (folded k_zero).
__global__ void k_wsplit(const float* __restrict__ W1, ushort* __restrict__ hi,
                         ushort* __restrict__ lo, int* __restrict__ gcnt) {
    int t = blockIdx.x * blockDim.x + threadIdx.x;
    if (t < 512) gcnt[t] = 0;
    if (t >= HID * KPAD) return;
    int ch = t / KPAD, k = t % KPAD;
    float v = (k < FIN) ? W1[k * HID + ch] : 0.0f;
    unsigned hu = bf16rne(v);
    float hf = __uint_as_float(hu << 16);
    unsigned lu = bf16rne(v - hf);
    hi[ch * KPAD + k] = (ushort)hu;
    lo[ch * KPAD + k] = (ushort)lu;
}

// coarse histogram by dst>>8 (int4 loads); persists per-block hist for k_bfill
__global__ __launch_bounds__(256) void k_bcount(const int* __restrict__ dst,
        int* __restrict__ gcnt, int* __restrict__ bhist, int ne) {
    __shared__ int hist[NBUCK];
    for (int i = threadIdx.x; i < NBUCK; i += 256) hist[i] = 0;
    __syncthreads();
    const int4* dst4 = (const int4*)dst;
    const int ne4 = ne >> 2;
    const int base4 = blockIdx.x * (CHUNK / 4);
#pragma unroll
    for (int it = 0; it < CHUNK / 1024; ++it) {
        int e4 = base4 + it * 256 + threadIdx.x;
        if (e4 < ne4) {
            int4 v = dst4[e4];
            atomicAdd(&hist[v.x >> 8], 1);
            atomicAdd(&hist[v.y >> 8], 1);
            atomicAdd(&hist[v.z >> 8], 1);
            atomicAdd(&hist[v.w >> 8], 1);
        }
    }
    if (blockIdx.x == 0 && threadIdx.x < (ne & 3))
        atomicAdd(&hist[dst[(ne & ~3) + threadIdx.x] >> 8], 1);
    __syncthreads();
    int* brow = bhist + (size_t)blockIdx.x * BH_STRIDE;
    for (int i = threadIdx.x; i < NBUCK; i += 256) {
        int h = hist[i];
        brow[i] = h;
        if (h) atomicAdd(&gcnt[i], h);
    }
}

__global__ __launch_bounds__(512) void k_bscan(const int* __restrict__ gcnt,
        int* __restrict__ gbase, int* __restrict__ gcur, int ne) {
    __shared__ int s[512];
    int tid = threadIdx.x;
    int v = (tid < NBUCK) ? gcnt[tid] : 0;
    s[tid] = v;
    __syncthreads();
    for (int off = 1; off < 512; off <<= 1) {
        int t = (tid >= off) ? s[tid - off] : 0;
        __syncthreads();
        s[tid] += t;
        __syncthreads();
    }
    if (tid < NBUCK) {
        int ex = s[tid] - v;
        gbase[tid] = ex;
        gcur[tid] = ex;
    }
    if (tid == 0) gbase[NBUCK] = ne;
}

// bucket fill: reuses k_bcount's histogram; int4 loads of src/dst
__global__ __launch_bounds__(256) void k_bfill(const int* __restrict__ src,
        const int* __restrict__ dst, int* __restrict__ gcur,
        const int* __restrict__ bhist, unsigned int* __restrict__ bucketed, int ne) {
    __shared__ int lcur[NBUCK];
    const int* brow = bhist + (size_t)blockIdx.x * BH_STRIDE;
    for (int i = threadIdx.x; i < NBUCK; i += 256) {
        int h = brow[i];
        lcur[i] = h ? atomicAdd(&gcur[i], h) : 0;
    }
    __syncthreads();
    const int4* dst4 = (const int4*)dst;
    const int4* src4 = (const int4*)src;
    const int ne4 = ne >> 2;
    const int base4 = blockIdx.x * (CHUNK / 4);
#pragma unroll
    for (int it = 0; it < CHUNK / 1024; ++it) {
        int e4 = base4 + it * 256 + threadIdx.x;
        if (e4 < ne4) {
            int4 d4 = dst4[e4];
            int4 s4 = src4[e4];
            int pos;
            pos = atomicAdd(&lcur[d4.x >> 8], 1);
            bucketed[pos] = (unsigned)s4.x | ((unsigned)(d4.x & 255) << 24);
            pos = atomicAdd(&lcur[d4.y >> 8], 1);
            bucketed[pos] = (unsigned)s4.y | ((unsigned)(d4.y & 255) << 24);
            pos = atomicAdd(&lcur[d4.z >> 8], 1);
            bucketed[pos] = (unsigned)s4.z | ((unsigned)(d4.z & 255) << 24);
            pos = atomicAdd(&lcur[d4.w >> 8], 1);
            bucketed[pos] = (unsigned)s4.w | ((unsigned)(d4.w & 255) << 24);
        }
    }
    if (blockIdx.x == 0 && threadIdx.x < (ne & 3)) {
        int e = (ne & ~3) + threadIdx.x;
        int d = dst[e];
        int pos = atomicAdd(&lcur[d >> 8], 1);
        bucketed[pos] = (unsigned)src[e] | ((unsigned)(d & 255) << 24);
    }
}

__global__ __launch_bounds__(256) void k_fine(const int* __restrict__ gbase,
        const unsigned int* __restrict__ bucketed, int* __restrict__ edata,
        int* __restrict__ rowptr, float* __restrict__ dinv, int n, int ne) {
    __shared__ int hist[256];
    __shared__ int scan[256];
    __shared__ int lcur[256];
    const int b = blockIdx.x;
    const int tid = threadIdx.x;
    const int beg = gbase[b], end = gbase[b + 1];
    hist[tid] = 0;
    __syncthreads();
    for (int j = beg + tid; j < end; j += 256)
        atomicAdd(&hist[bucketed[j] >> 24], 1);
    __syncthreads();
    int c = hist[tid];
    scan[tid] = c;
    __syncthreads();
    for (int off = 1; off < 256; off <<= 1) {
        int t = (tid >= off) ? scan[tid - off] : 0;
        __syncthreads();
        scan[tid] += t;
        __syncthreads();
    }
    int excl = scan[tid] - c;
    int d = b * 256 + tid;
    if (d < n) {
        rowptr[d] = beg + excl;
        dinv[d] = rsqrtf((float)c + 1.0f);   // +1 self-loop
    }
    lcur[tid] = beg + excl;
    __syncthreads();
    for (int j = beg + tid; j < end; j += 256) {
        unsigned p = bucketed[j];
        int pos = atomicAdd(&lcur[p >> 24], 1);
        edata[pos] = (int)(p & 0x00FFFFFFu);
    }
    if (b == NBUCK - 1 && tid == 0) rowptr[n] = ne;
}

// h1 = x @ W1 via MFMA: x plain bf16 (single round — absmax-neutral per R9),
// W split hi/lo staged in LDS (acc += Ah*Bh + Ah*Bl). 64 nodes/block.
// h1 packed: uint [node][u] = bf16(ch=u) | bf16(ch=u+64)<<16.
__global__ __launch_bounds__(256) void k_gemm1(const float* __restrict__ x,
        const ushort* __restrict__ wthi, const ushort* __restrict__ wtlo,
        unsigned* __restrict__ h1, int n) {
    __shared__ alignas(16) ushort xhi[64 * 40];
    __shared__ alignas(16) ushort whi[128 * 40], wlo[128 * 40];
    const int tid = threadIdx.x;
    const int node0 = blockIdx.x * 64;
    const int wv = tid >> 6, lane = tid & 63;
    const int r15 = lane & 15, g = lane >> 4;
    f32x4 acc[8];
#pragma unroll
    for (int ct = 0; ct < 8; ++ct) acc[ct] = (f32x4){0.f, 0.f, 0.f, 0.f};

    const int snd = tid >> 2, sq = tid & 3;     // x staging: 4 threads/node, 8 k each
    const int sch = tid >> 1, sh = tid & 1;     // W staging: 2 threads/ch, 16 k each

    for (int ks = 0; ks < 6; ++ks) {
        {
            int gidx = sch * KPAD + ks * 32 + sh * 16;
            int lidx = sch * 40 + sh * 16;
            uint4 a = *(const uint4*)&wthi[gidx];
            uint4 b = *(const uint4*)&wthi[gidx + 8];
            *(uint4*)&whi[lidx] = a;
            *(uint4*)&whi[lidx + 8] = b;
            uint4 c = *(const uint4*)&wtlo[gidx];
            uint4 d2 = *(const uint4*)&wtlo[gidx + 8];
            *(uint4*)&wlo[lidx] = c;
            *(uint4*)&wlo[lidx + 8] = d2;
        }
        {
            int node = node0 + snd;
            unsigned h8[8];
#pragma unroll
            for (int j = 0; j < 8; ++j) {
                int kk = ks * 32 + sq * 8 + j;
                float v = (node < n && kk < FIN) ? x[node * FIN + kk] : 0.0f;
                h8[j] = bf16rne(v);
            }
            int lidx = snd * 40 + sq * 8;
            *(uint4*)&xhi[lidx] = make_uint4(h8[0] | (h8[1] << 16), h8[2] | (h8[3] << 16),
                                             h8[4] | (h8[5] << 16), h8[6] | (h8[7] << 16));
        }
        __syncthreads();
        short8 Ah = ldfrag(&xhi[(wv * 16 + r15) * 40 + 4 * g]);
#pragma unroll
        for (int ct = 0; ct < 8; ++ct) {
            short8 Bh = ldfrag(&whi[(ct * 16 + r15) * 40 + 4 * g]);
            short8 Bl = ldfrag(&wlo[(ct * 16 + r15) * 40 + 4 * g]);
            acc[ct] = __builtin_amdgcn_mfma_f32_16x16x32_bf16(Ah, Bh, acc[ct], 0, 0, 0);
            acc[ct] = __builtin_amdgcn_mfma_f32_16x16x32_bf16(Ah, Bl, acc[ct], 0, 0, 0);
        }
        __syncthreads();
    }
#pragma unroll
    for (int ct = 0; ct < 4; ++ct) {
#pragma unroll
        for (int r = 0; r < 4; ++r) {
            int node = node0 + wv * 16 + 4 * g + r;
            if (node < n) {
                unsigned p = bf16rne(acc[ct][r]) | (bf16rne(acc[ct + 4][r]) << 16);
                h1[node * 64 + ct * 16 + r15] = p;
            }
        }
    }
}

// one wave per dst node; 16 edges per iteration (4 per 16-lane group), with
// software-pipelined (src, norm) prefetch. L2-miss-BW bound (~3.3 TB/s).
// Processes nodes [n0, n0+nn) — launched twice so mid-tier kernels surface
// in the rocprof top-5.
__global__ __launch_bounds__(256) void k_agg_fused(const int* __restrict__ rowptr,
        const int* __restrict__ edata, const unsigned int* __restrict__ h1,
        const float* __restrict__ dinv, const float* __restrict__ b1,
        const float* __restrict__ W2, float* __restrict__ z, int n0, int nn) {
    const int wid  = (blockIdx.x * blockDim.x + threadIdx.x) >> 6;
    const int lane = threadIdx.x & 63;
    if (wid >= nn) return;
    const int d = n0 + wid;
    const int beg = rowptr[d], end = rowptr[d + 1];
    const float di = dinv[d];
    const int grp = lane >> 4;          // which edge slot of the 4-pack
    const int sl  = lane & 15;          // channel slice: uints sl*4..sl*4+3

    float ax0, ax1, ax2, ax3, ay0, ay1, ay2, ay3;
    {   // self-loop (group 0 only, weight di^2)
        uint4 hv = *(const uint4*)&h1[d * 64 + sl * 4];
        float nm = (grp == 0) ? di * di : 0.0f;
        float2 f0 = bf2_to_f2(hv.x), f1 = bf2_to_f2(hv.y);
        float2 f2 = bf2_to_f2(hv.z), f3 = bf2_to_f2(hv.w);
        ax0 = f0.x * nm; ay0 = f0.y * nm;
        ax1 = f1.x * nm; ay1 = f1.y * nm;
        ax2 = f2.x * nm; ay2 = f2.y * nm;
        ax3 = f3.x * nm; ay3 = f3.y * nm;
    }

#define PRELOAD(JB)                                                          \
    {                                                                        \
        int i0 = (JB) + grp, i1 = (JB) + 4 + grp,                            \
            i2 = (JB) + 8 + grp, i3 = (JB) + 12 + grp;                       \
        int c0 = min(i0, end - 1), c1 = min(i1, end - 1);                    \
        int c2 = min(i2, end - 1), c3 = min(i3, end - 1);                    \
        s0 = edata[c0]; s1 = edata[c1]; s2 = edata[c2]; s3 = edata[c3];      \
        m0 = (i0 < end) ? dinv[s0] * di : 0.0f;                              \
        m1 = (i1 < end) ? dinv[s1] * di : 0.0f;                              \
        m2 = (i2 < end) ? dinv[s2] * di : 0.0f;                              \
        m3 = (i3 < end) ? dinv[s3] * di : 0.0f;                              \
    }
#define ACC(G, NM)                                                           \
    {                                                                        \
        float2 f;                                                            \
        f = bf2_to_f2((G).x); ax0 = fmaf(f.x, (NM), ax0); ay0 = fmaf(f.y, (NM), ay0); \
        f = bf2_to_f2((G).y); ax1 = fmaf(f.x, (NM), ax1); ay1 = fmaf(f.y, (NM), ay1); \
        f = bf2_to_f2((G).z); ax2 = fmaf(f.x, (NM), ax2); ay2 = fmaf(f.y, (NM), ay2); \
        f = bf2_to_f2((G).w); ax3 = fmaf(f.x, (NM), ax3); ay3 = fmaf(f.y, (NM), ay3); \
    }

    if (beg < end) {
        int s0, s1, s2, s3;
        float m0, m1, m2, m3;
        PRELOAD(beg);
        for (int j = beg; j < end; j += 16) {
            uint4 g0 = *(const uint4*)&h1[s0 * 64 + sl * 4];
            uint4 g1 = *(const uint4*)&h1[s1 * 64 + sl * 4];
            uint4 g2 = *(const uint4*)&h1[s2 * 64 + sl * 4];
            uint4 g3 = *(const uint4*)&h1[s3 * 64 + sl * 4];
            float w0 = m0, w1 = m1, w2 = m2, w3 = m3;
            int jn = j + 16;
            if (jn < end) PRELOAD(jn);          // wave-uniform branch
            ACC(g0, w0); ACC(g1, w1); ACC(g2, w2); ACC(g3, w3);
        }
    }
#undef PRELOAD
#undef ACC

    ax0 += __shfl_xor(ax0, 16, 64); ax0 += __shfl_xor(ax0, 32, 64);
    ax1 += __shfl_xor(ax1, 16, 64); ax1 += __shfl_xor(ax1, 32, 64);
    ax2 += __shfl_xor(ax2, 16, 64); ax2 += __shfl_xor(ax2, 32, 64);
    ax3 += __shfl_xor(ax3, 16, 64); ax3 += __shfl_xor(ax3, 32, 64);
    ay0 += __shfl_xor(ay0, 16, 64); ay0 += __shfl_xor(ay0, 32, 64);
    ay1 += __shfl_xor(ay1, 16, 64); ay1 += __shfl_xor(ay1, 32, 64);
    ay2 += __shfl_xor(ay2, 16, 64); ay2 += __shfl_xor(ay2, 32, 64);
    ay3 += __shfl_xor(ay3, 16, 64); ay3 += __shfl_xor(ay3, 32, 64);
    // epilogue: channels c=sl*4+q (ax) and c+64 (ay); relu + W2 dot
    const int c = sl * 4;
    float4 bA = *(const float4*)&b1[c];
    float4 bB = *(const float4*)&b1[c + 64];
    float v00 = ax0 + bA.x; v00 = v00 > 0.f ? v00 : 0.f;
    float v01 = ax1 + bA.y; v01 = v01 > 0.f ? v01 : 0.f;
    float v02 = ax2 + bA.z; v02 = v02 > 0.f ? v02 : 0.f;
    float v03 = ax3 + bA.w; v03 = v03 > 0.f ? v03 : 0.f;
    float v10 = ay0 + bB.x; v10 = v10 > 0.f ? v10 : 0.f;
    float v11 = ay1 + bB.y; v11 = v11 > 0.f ? v11 : 0.f;
    float v12 = ay2 + bB.z; v12 = v12 > 0.f ? v12 : 0.f;
    float v13 = ay3 + bB.w; v13 = v13 > 0.f ? v13 : 0.f;
    float4 wA0 = *(const float4*)&W2[c * 2];
    float4 wA1 = *(const float4*)&W2[c * 2 + 4];
    float4 wB0 = *(const float4*)&W2[(c + 64) * 2];
    float4 wB1 = *(const float4*)&W2[(c + 64) * 2 + 4];
    float p0 = v00 * wA0.x + v01 * wA0.z + v02 * wA1.x + v03 * wA1.z
             + v10 * wB0.x + v11 * wB0.z + v12 * wB1.x + v13 * wB1.z;
    float p1 = v00 * wA0.y + v01 * wA0.w + v02 * wA1.y + v03 * wA1.w
             + v10 * wB0.y + v11 * wB0.w + v12 * wB1.y + v13 * wB1.w;
#pragma unroll
    for (int m = 8; m >= 1; m >>= 1) {
        p0 += __shfl_xor(p0, m, 64);
        p1 += __shfl_xor(p1, m, 64);
    }
    if (lane == 0) *(float2*)&z[d * 2] = make_float2(p0, p1);
}

// layer-2: 16-lane group per dst node, gather-side over the same CSR
__global__ __launch_bounds__(256) void k_out(const int* __restrict__ rowptr,
        const int* __restrict__ edata, const float* __restrict__ z,
        const float* __restrict__ dinv, const float* __restrict__ b2,
        float* __restrict__ out, int n) {
    int g = (blockIdx.x * blockDim.x + threadIdx.x) >> 4;
    int l = threadIdx.x & 15;
    if (g >= n) return;
    int beg = rowptr[g], end = rowptr[g + 1];
    float di = dinv[g];
    float o0 = 0.0f, o1 = 0.0f;
    for (int j = beg + l; j < end; j += 16) {
        int s = edata[j];
        float nm = dinv[s] * di;
        float2 zs = *(const float2*)&z[s * 2];
        o0 = fmaf(zs.x, nm, o0);
        o1 = fmaf(zs.y, nm, o1);
    }
#pragma unroll
    for (int m = 8; m >= 1; m >>= 1) {
        o0 += __shfl_xor(o0, m, 16);
        o1 += __shfl_xor(o1, m, 16);
    }
    if (l == 0) {
        float2 zd = *(const float2*)&z[g * 2];
        float s2 = di * di;
        out[g * 2]     = fmaf(zd.x, s2, b2[0]) + o0;
        out[g * 2 + 1] = fmaf(zd.y, s2, b2[1]) + o1;
    }
}

extern "C" void kernel_launch(void* const* d_in, const int* in_sizes, int n_in,
                              void* d_out, int out_size, void* d_ws, size_t ws_size,
                              hipStream_t stream) {
    const float* x  = (const float*)d_in[0];
    const int*   ei = (const int*)d_in[1];
    const float* W1 = (const float*)d_in[2];
    const float* b1 = (const float*)d_in[3];
    const float* W2 = (const float*)d_in[4];
    const float* b2 = (const float*)d_in[5];
    float* out = (float*)d_out;

    const int n  = in_sizes[0] / FIN;   // 100000
    const int ne = in_sizes[1] / 2;     // 3200000
    const int* src = ei;
    const int* dst = ei + ne;

    float* ws     = (float*)d_ws;
    float* dinv   = ws + OFF_DINV;
    unsigned int* h1 = (unsigned int*)(ws + OFF_H1);
    float* z      = ws + OFF_Z;
    int*   rowptr = (int*)(ws + OFF_ROWPTR);
    int*   gcnt   = (int*)(ws + OFF_GCNT);
    int*   gbase  = (int*)(ws + OFF_GBASE);
    int*   gcur   = (int*)(ws + OFF_GCUR);
    unsigned int* bucketed = (unsigned int*)(ws + OFF_BUCK);
    int*   edata  = (int*)(ws + OFF_EDATA);
    ushort* wthi  = (ushort*)(ws + OFF_WTHI);
    ushort* wtlo  = (ushort*)(ws + OFF_WTLO);
    int*   bhist  = (int*)(ws + OFF_BHIST);

    const int nchb = (ne + CHUNK - 1) / CHUNK;   // 1563

    k_wsplit<<<(HID * KPAD + 255) / 256, 256, 0, stream>>>(W1, wthi, wtlo, gcnt);
    k_bcount<<<nchb, 256, 0, stream>>>(dst, gcnt, bhist, ne);
    k_bscan<<<1, 512, 0, stream>>>(gcnt, gbase, gcur, ne);
    k_bfill<<<nchb, 256, 0, stream>>>(src, dst, gcur, bhist, bucketed, ne);
    k_fine<<<NBUCK, 256, 0, stream>>>(gbase, bucketed, edata, rowptr, dinv, n, ne);
    k_gemm1<<<(n + 63) / 64, 256, 0, stream>>>(x, wthi, wtlo, h1, n);
    const int half = (n + 1) / 2;
    k_agg_fused<<<(half * 64 + 255) / 256, 256, 0, stream>>>(rowptr, edata, h1, dinv, b1, W2, z, 0, half);
    k_agg_fused<<<((n - half) * 64 + 255) / 256, 256, 0, stream>>>(rowptr, edata, h1, dinv, b1, W2, z, half, n - half);
    k_out<<<(n * 16 + 255) / 256, 256, 0, stream>>>(rowptr, edata, z, dinv, b2, out, n);
}

// Round 12
// 269.330 us; speedup vs baseline: 1.2096x; 1.2096x over previous
//
#include <hip/hip_runtime.h>

#define NN  100000
#define FIN 165
#define HID 128
#define NBUCK 391        // ceil(NN/256), bucket = dst >> 8
#define CHUNK 8192       // edges per block in bucket passes (write-locality sweet spot)
#define KPAD 192         // FIN padded to 6 k-steps of 32
#define BH_STRIDE 400    // per-block histogram row stride

typedef __attribute__((ext_vector_type(4))) float f32x4;
typedef __attribute__((ext_vector_type(8))) short short8;

// ws layout (4-byte units). h1 packed uint = bf16 pair (ch, ch+64) per node.
#define OFF_DINV   0
#define OFF_H1     100352
#define OFF_Z      (OFF_H1 + NN * 64)
#define OFF_ROWPTR (OFF_Z + 2 * NN)
#define OFF_GCNT   (OFF_ROWPTR + 100352)
#define OFF_GBASE  (OFF_GCNT + 512)
#define OFF_GCUR   (OFF_GBASE + 512)
#define OFF_BUCK   (OFF_GCUR + 512)
#define OFF_EDATA  (OFF_BUCK + 3200000)
#define OFF_WTHI   (OFF_EDATA + 3200000)          // 128*KPAD ushorts = 12288 uints
#define OFF_WTLO   (OFF_WTHI + 12288)
#define OFF_BHIST  (OFF_WTLO + 12288)             // nchb(391) * BH_STRIDE ints ~= 157k
// end ~= 13.5M * 4B ~= 54 MB

__device__ __forceinline__ unsigned bf16rne(float f) {
    unsigned u = __float_as_uint(f);
    return (u + 0x7FFFu + ((u >> 16) & 1u)) >> 16;
}

__device__ __forceinline__ float2 bf2_to_f2(unsigned int u) {
    float2 r;
    r.x = __uint_as_float(u << 16);
    r.y = __uint_as_float(u & 0xffff0000u);
    return r;
}

__device__ __forceinline__ short8 ldfrag(const ushort* p) {
    union { uint2 u[2]; short8 s; } f;
    f.u[0] = *(const uint2*)p;          // k = 4g .. 4g+3
    f.u[1] = *(const uint2*)(p + 16);   // k = 16+4g .. 16+4g+3
    return f.s;
}

// split W1 into bf16 hi/lo, transposed to [ch][k] with K zero-padded to KPAD.
// Also zeroes gcnt (folded k_zero).
__global__ void k_wsplit(const float* __restrict__ W1, ushort* __restrict__ hi,
                         ushort* __restrict__ lo, int* __restrict__ gcnt) {
    int t = blockIdx.x * blockDim.x + threadIdx.x;
    if (t < 512) gcnt[t] = 0;
    if (t >= HID * KPAD) return;
    int ch = t / KPAD, k = t % KPAD;
    float v = (k < FIN) ? W1[k * HID + ch] : 0.0f;
    unsigned hu = bf16rne(v);
    float hf = __uint_as_float(hu << 16);
    unsigned lu = bf16rne(v - hf);
    hi[ch * KPAD + k] = (ushort)hu;
    lo[ch * KPAD + k] = (ushort)lu;
}

// coarse histogram by dst>>8 (int4 loads); persists per-block hist for k_bfill
__global__ __launch_bounds__(256) void k_bcount(const int* __restrict__ dst,
        int* __restrict__ gcnt, int* __restrict__ bhist, int ne) {
    __shared__ int hist[NBUCK];
    for (int i = threadIdx.x; i < NBUCK; i += 256) hist[i] = 0;
    __syncthreads();
    const int4* dst4 = (const int4*)dst;
    const int ne4 = ne >> 2;
    const int base4 = blockIdx.x * (CHUNK / 4);
#pragma unroll
    for (int it = 0; it < CHUNK / 1024; ++it) {
        int e4 = base4 + it * 256 + threadIdx.x;
        if (e4 < ne4) {
            int4 v = dst4[e4];
            atomicAdd(&hist[v.x >> 8], 1);
            atomicAdd(&hist[v.y >> 8], 1);
            atomicAdd(&hist[v.z >> 8], 1);
            atomicAdd(&hist[v.w >> 8], 1);
        }
    }
    if (blockIdx.x == 0 && threadIdx.x < (ne & 3))
        atomicAdd(&hist[dst[(ne & ~3) + threadIdx.x] >> 8], 1);
    __syncthreads();
    int* brow = bhist + (size_t)blockIdx.x * BH_STRIDE;
    for (int i = threadIdx.x; i < NBUCK; i += 256) {
        int h = hist[i];
        brow[i] = h;
        if (h) atomicAdd(&gcnt[i], h);
    }
}

__global__ __launch_bounds__(512) void k_bscan(const int* __restrict__ gcnt,
        int* __restrict__ gbase, int* __restrict__ gcur, int ne) {
    __shared__ int s[512];
    int tid = threadIdx.x;
    int v = (tid < NBUCK) ? gcnt[tid] : 0;
    s[tid] = v;
    __syncthreads();
    for (int off = 1; off < 512; off <<= 1) {
        int t = (tid >= off) ? s[tid - off] : 0;
        __syncthreads();
        s[tid] += t;
        __syncthreads();
    }
    if (tid < NBUCK) {
        int ex = s[tid] - v;
        gbase[tid] = ex;
        gcur[tid] = ex;
    }
    if (tid == 0) gbase[NBUCK] = ne;
}

// bucket fill: reuses k_bcount's histogram; int4 loads of src/dst
__global__ __launch_bounds__(256) void k_bfill(const int* __restrict__ src,
        const int* __restrict__ dst, int* __restrict__ gcur,
        const int* __restrict__ bhist, unsigned int* __restrict__ bucketed, int ne) {
    __shared__ int lcur[NBUCK];
    const int* brow = bhist + (size_t)blockIdx.x * BH_STRIDE;
    for (int i = threadIdx.x; i < NBUCK; i += 256) {
        int h = brow[i];
        lcur[i] = h ? atomicAdd(&gcur[i], h) : 0;
    }
    __syncthreads();
    const int4* dst4 = (const int4*)dst;
    const int4* src4 = (const int4*)src;
    const int ne4 = ne >> 2;
    const int base4 = blockIdx.x * (CHUNK / 4);
#pragma unroll
    for (int it = 0; it < CHUNK / 1024; ++it) {
        int e4 = base4 + it * 256 + threadIdx.x;
        if (e4 < ne4) {
            int4 d4 = dst4[e4];
            int4 s4 = src4[e4];
            int pos;
            pos = atomicAdd(&lcur[d4.x >> 8], 1);
            bucketed[pos] = (unsigned)s4.x | ((unsigned)(d4.x & 255) << 24);
            pos = atomicAdd(&lcur[d4.y >> 8], 1);
            bucketed[pos] = (unsigned)s4.y | ((unsigned)(d4.y & 255) << 24);
            pos = atomicAdd(&lcur[d4.z >> 8], 1);
            bucketed[pos] = (unsigned)s4.z | ((unsigned)(d4.z & 255) << 24);
            pos = atomicAdd(&lcur[d4.w >> 8], 1);
            bucketed[pos] = (unsigned)s4.w | ((unsigned)(d4.w & 255) << 24);
        }
    }
    if (blockIdx.x == 0 && threadIdx.x < (ne & 3)) {
        int e = (ne & ~3) + threadIdx.x;
        int d = dst[e];
        int pos = atomicAdd(&lcur[d >> 8], 1);
        bucketed[pos] = (unsigned)src[e] | ((unsigned)(d & 255) << 24);
    }
}

__global__ __launch_bounds__(256) void k_fine(const int* __restrict__ gbase,
        const unsigned int* __restrict__ bucketed, int* __restrict__ edata,
        int* __restrict__ rowptr, float* __restrict__ dinv, int n, int ne) {
    __shared__ int hist[256];
    __shared__ int scan[256];
    __shared__ int lcur[256];
    const int b = blockIdx.x;
    const int tid = threadIdx.x;
    const int beg = gbase[b], end = gbase[b + 1];
    hist[tid] = 0;
    __syncthreads();
    for (int j = beg + tid; j < end; j += 256)
        atomicAdd(&hist[bucketed[j] >> 24], 1);
    __syncthreads();
    int c = hist[tid];
    scan[tid] = c;
    __syncthreads();
    for (int off = 1; off < 256; off <<= 1) {
        int t = (tid >= off) ? scan[tid - off] : 0;
        __syncthreads();
        scan[tid] += t;
        __syncthreads();
    }
    int excl = scan[tid] - c;
    int d = b * 256 + tid;
    if (d < n) {
        rowptr[d] = beg + excl;
        dinv[d] = rsqrtf((float)c + 1.0f);   // +1 self-loop
    }
    lcur[tid] = beg + excl;
    __syncthreads();
    for (int j = beg + tid; j < end; j += 256) {
        unsigned p = bucketed[j];
        int pos = atomicAdd(&lcur[p >> 24], 1);
        edata[pos] = (int)(p & 0x00FFFFFFu);
    }
    if (b == NBUCK - 1 && tid == 0) rowptr[n] = ne;
}

// h1 = x @ W1 via MFMA: x plain bf16 (single round — absmax-neutral per R9),
// W split hi/lo staged in LDS (acc += Ah*Bh + Ah*Bl). 64 nodes/block.
// h1 packed: uint [node][u] = bf16(ch=u) | bf16(ch=u+64)<<16.
__global__ __launch_bounds__(256) void k_gemm1(const float* __restrict__ x,
        const ushort* __restrict__ wthi, const ushort* __restrict__ wtlo,
        unsigned* __restrict__ h1, int n) {
    __shared__ alignas(16) ushort xhi[64 * 40];
    __shared__ alignas(16) ushort whi[128 * 40], wlo[128 * 40];
    const int tid = threadIdx.x;
    const int node0 = blockIdx.x * 64;
    const int wv = tid >> 6, lane = tid & 63;
    const int r15 = lane & 15, g = lane >> 4;
    f32x4 acc[8];
#pragma unroll
    for (int ct = 0; ct < 8; ++ct) acc[ct] = (f32x4){0.f, 0.f, 0.f, 0.f};

    const int snd = tid >> 2, sq = tid & 3;     // x staging: 4 threads/node, 8 k each
    const int sch = tid >> 1, sh = tid & 1;     // W staging: 2 threads/ch, 16 k each

    for (int ks = 0; ks < 6; ++ks) {
        {
            int gidx = sch * KPAD + ks * 32 + sh * 16;
            int lidx = sch * 40 + sh * 16;
            uint4 a = *(const uint4*)&wthi[gidx];
            uint4 b = *(const uint4*)&wthi[gidx + 8];
            *(uint4*)&whi[lidx] = a;
            *(uint4*)&whi[lidx + 8] = b;
            uint4 c = *(const uint4*)&wtlo[gidx];
            uint4 d2 = *(const uint4*)&wtlo[gidx + 8];
            *(uint4*)&wlo[lidx] = c;
            *(uint4*)&wlo[lidx + 8] = d2;
        }
        {
            int node = node0 + snd;
            unsigned h8[8];
#pragma unroll
            for (int j = 0; j < 8; ++j) {
                int kk = ks * 32 + sq * 8 + j;
                float v = (node < n && kk < FIN) ? x[node * FIN + kk] : 0.0f;
                h8[j] = bf16rne(v);
            }
            int lidx = snd * 40 + sq * 8;
            *(uint4*)&xhi[lidx] = make_uint4(h8[0] | (h8[1] << 16), h8[2] | (h8[3] << 16),
                                             h8[4] | (h8[5] << 16), h8[6] | (h8[7] << 16));
        }
        __syncthreads();
        short8 Ah = ldfrag(&xhi[(wv * 16 + r15) * 40 + 4 * g]);
#pragma unroll
        for (int ct = 0; ct < 8; ++ct) {
            short8 Bh = ldfrag(&whi[(ct * 16 + r15) * 40 + 4 * g]);
            short8 Bl = ldfrag(&wlo[(ct * 16 + r15) * 40 + 4 * g]);
            acc[ct] = __builtin_amdgcn_mfma_f32_16x16x32_bf16(Ah, Bh, acc[ct], 0, 0, 0);
            acc[ct] = __builtin_amdgcn_mfma_f32_16x16x32_bf16(Ah, Bl, acc[ct], 0, 0, 0);
        }
        __syncthreads();
    }
#pragma unroll
    for (int ct = 0; ct < 4; ++ct) {
#pragma unroll
        for (int r = 0; r < 4; ++r) {
            int node = node0 + wv * 16 + 4 * g + r;
            if (node < n) {
                unsigned p = bf16rne(acc[ct][r]) | (bf16rne(acc[ct + 4][r]) << 16);
                h1[node * 64 + ct * 16 + r15] = p;
            }
        }
    }
}

// one wave per dst node; 16 edges per iteration (4 per 16-lane group), with
// software-pipelined (src, norm) prefetch. L2-miss-BW bound (~3.3 TB/s).
// Processes nodes [n0, n0+nn) — launched twice for rocprof visibility.
__global__ __launch_bounds__(256) void k_agg_fused(const int* __restrict__ rowptr,
        const int* __restrict__ edata, const unsigned int* __restrict__ h1,
        const float* __restrict__ dinv, const float* __restrict__ b1,
        const float* __restrict__ W2, float* __restrict__ z, int n0, int nn) {
    const int wid  = (blockIdx.x * blockDim.x + threadIdx.x) >> 6;
    const int lane = threadIdx.x & 63;
    if (wid >= nn) return;
    const int d = n0 + wid;
    const int beg = rowptr[d], end = rowptr[d + 1];
    const float di = dinv[d];
    const int grp = lane >> 4;          // which edge slot of the 4-pack
    const int sl  = lane & 15;          // channel slice: uints sl*4..sl*4+3

    float ax0, ax1, ax2, ax3, ay0, ay1, ay2, ay3;
    {   // self-loop (group 0 only, weight di^2)
        uint4 hv = *(const uint4*)&h1[d * 64 + sl * 4];
        float nm = (grp == 0) ? di * di : 0.0f;
        float2 f0 = bf2_to_f2(hv.x), f1 = bf2_to_f2(hv.y);
        float2 f2 = bf2_to_f2(hv.z), f3 = bf2_to_f2(hv.w);
        ax0 = f0.x * nm; ay0 = f0.y * nm;
        ax1 = f1.x * nm; ay1 = f1.y * nm;
        ax2 = f2.x * nm; ay2 = f2.y * nm;
        ax3 = f3.x * nm; ay3 = f3.y * nm;
    }

#define PRELOAD(JB)                                                          \
    {                                                                        \
        int i0 = (JB) + grp, i1 = (JB) + 4 + grp,                            \
            i2 = (JB) + 8 + grp, i3 = (JB) + 12 + grp;                       \
        int c0 = min(i0, end - 1), c1 = min(i1, end - 1);                    \
        int c2 = min(i2, end - 1), c3 = min(i3, end - 1);                    \
        s0 = edata[c0]; s1 = edata[c1]; s2 = edata[c2]; s3 = edata[c3];      \
        m0 = (i0 < end) ? dinv[s0] * di : 0.0f;                              \
        m1 = (i1 < end) ? dinv[s1] * di : 0.0f;                              \
        m2 = (i2 < end) ? dinv[s2] * di : 0.0f;                              \
        m3 = (i3 < end) ? dinv[s3] * di : 0.0f;                              \
    }
#define ACC(G, NM)                                                           \
    {                                                                        \
        float2 f;                                                            \
        f = bf2_to_f2((G).x); ax0 = fmaf(f.x, (NM), ax0); ay0 = fmaf(f.y, (NM), ay0); \
        f = bf2_to_f2((G).y); ax1 = fmaf(f.x, (NM), ax1); ay1 = fmaf(f.y, (NM), ay1); \
        f = bf2_to_f2((G).z); ax2 = fmaf(f.x, (NM), ax2); ay2 = fmaf(f.y, (NM), ay2); \
        f = bf2_to_f2((G).w); ax3 = fmaf(f.x, (NM), ax3); ay3 = fmaf(f.y, (NM), ay3); \
    }

    if (beg < end) {
        int s0, s1, s2, s3;
        float m0, m1, m2, m3;
        PRELOAD(beg);
        for (int j = beg; j < end; j += 16) {
            uint4 g0 = *(const uint4*)&h1[s0 * 64 + sl * 4];
            uint4 g1 = *(const uint4*)&h1[s1 * 64 + sl * 4];
            uint4 g2 = *(const uint4*)&h1[s2 * 64 + sl * 4];
            uint4 g3 = *(const uint4*)&h1[s3 * 64 + sl * 4];
            float w0 = m0, w1 = m1, w2 = m2, w3 = m3;
            int jn = j + 16;
            if (jn < end) PRELOAD(jn);          // wave-uniform branch
            ACC(g0, w0); ACC(g1, w1); ACC(g2, w2); ACC(g3, w3);
        }
    }
#undef PRELOAD
#undef ACC

    ax0 += __shfl_xor(ax0, 16, 64); ax0 += __shfl_xor(ax0, 32, 64);
    ax1 += __shfl_xor(ax1, 16, 64); ax1 += __shfl_xor(ax1, 32, 64);
    ax2 += __shfl_xor(ax2, 16, 64); ax2 += __shfl_xor(ax2, 32, 64);
    ax3 += __shfl_xor(ax3, 16, 64); ax3 += __shfl_xor(ax3, 32, 64);
    ay0 += __shfl_xor(ay0, 16, 64); ay0 += __shfl_xor(ay0, 32, 64);
    ay1 += __shfl_xor(ay1, 16, 64); ay1 += __shfl_xor(ay1, 32, 64);
    ay2 += __shfl_xor(ay2, 16, 64); ay2 += __shfl_xor(ay2, 32, 64);
    ay3 += __shfl_xor(ay3, 16, 64); ay3 += __shfl_xor(ay3, 32, 64);
    // epilogue: channels c=sl*4+q (ax) and c+64 (ay); relu + W2 dot
    const int c = sl * 4;
    float4 bA = *(const float4*)&b1[c];
    float4 bB = *(const float4*)&b1[c + 64];
    float v00 = ax0 + bA.x; v00 = v00 > 0.f ? v00 : 0.f;
    float v01 = ax1 + bA.y; v01 = v01 > 0.f ? v01 : 0.f;
    float v02 = ax2 + bA.z; v02 = v02 > 0.f ? v02 : 0.f;
    float v03 = ax3 + bA.w; v03 = v03 > 0.f ? v03 : 0.f;
    float v10 = ay0 + bB.x; v10 = v10 > 0.f ? v10 : 0.f;
    float v11 = ay1 + bB.y; v11 = v11 > 0.f ? v11 : 0.f;
    float v12 = ay2 + bB.z; v12 = v12 > 0.f ? v12 : 0.f;
    float v13 = ay3 + bB.w; v13 = v13 > 0.f ? v13 : 0.f;
    float4 wA0 = *(const float4*)&W2[c * 2];
    float4 wA1 = *(const float4*)&W2[c * 2 + 4];
    float4 wB0 = *(const float4*)&W2[(c + 64) * 2];
    float4 wB1 = *(const float4*)&W2[(c + 64) * 2 + 4];
    float p0 = v00 * wA0.x + v01 * wA0.z + v02 * wA1.x + v03 * wA1.z
             + v10 * wB0.x + v11 * wB0.z + v12 * wB1.x + v13 * wB1.z;
    float p1 = v00 * wA0.y + v01 * wA0.w + v02 * wA1.y + v03 * wA1.w
             + v10 * wB0.y + v11 * wB0.w + v12 * wB1.y + v13 * wB1.w;
#pragma unroll
    for (int m = 8; m >= 1; m >>= 1) {
        p0 += __shfl_xor(p0, m, 64);
        p1 += __shfl_xor(p1, m, 64);
    }
    if (lane == 0) *(float2*)&z[d * 2] = make_float2(p0, p1);
}

// layer-2: 16-lane group per dst node, gather-side over the same CSR
__global__ __launch_bounds__(256) void k_out(const int* __restrict__ rowptr,
        const int* __restrict__ edata, const float* __restrict__ z,
        const float* __restrict__ dinv, const float* __restrict__ b2,
        float* __restrict__ out, int n) {
    int g = (blockIdx.x * blockDim.x + threadIdx.x) >> 4;
    int l = threadIdx.x & 15;
    if (g >= n) return;
    int beg = rowptr[g], end = rowptr[g + 1];
    float di = dinv[g];
    float o0 = 0.0f, o1 = 0.0f;
    for (int j = beg + l; j < end; j += 16) {
        int s = edata[j];
        float nm = dinv[s] * di;
        float2 zs = *(const float2*)&z[s * 2];
        o0 = fmaf(zs.x, nm, o0);
        o1 = fmaf(zs.y, nm, o1);
    }
#pragma unroll
    for (int m = 8; m >= 1; m >>= 1) {
        o0 += __shfl_xor(o0, m, 16);
        o1 += __shfl_xor(o1, m, 16);
    }
    if (l == 0) {
        float2 zd = *(const float2*)&z[g * 2];
        float s2 = di * di;
        out[g * 2]     = fmaf(zd.x, s2, b2[0]) + o0;
        out[g * 2 + 1] = fmaf(zd.y, s2, b2[1]) + o1;
    }
}

extern "C" void kernel_launch(void* const* d_in, const int* in_sizes, int n_in,
                              void* d_out, int out_size, void* d_ws, size_t ws_size,
                              hipStream_t stream) {
    const float* x  = (const float*)d_in[0];
    const int*   ei = (const int*)d_in[1];
    const float* W1 = (const float*)d_in[2];
    const float* b1 = (const float*)d_in[3];
    const float* W2 = (const float*)d_in[4];
    const float* b2 = (const float*)d_in[5];
    float* out = (float*)d_out;

    const int n  = in_sizes[0] / FIN;   // 100000
    const int ne = in_sizes[1] / 2;     // 3200000
    const int* src = ei;
    const int* dst = ei + ne;

    float* ws     = (float*)d_ws;
    float* dinv   = ws + OFF_DINV;
    unsigned int* h1 = (unsigned int*)(ws + OFF_H1);
    float* z      = ws + OFF_Z;
    int*   rowptr = (int*)(ws + OFF_ROWPTR);
    int*   gcnt   = (int*)(ws + OFF_GCNT);
    int*   gbase  = (int*)(ws + OFF_GBASE);
    int*   gcur   = (int*)(ws + OFF_GCUR);
    unsigned int* bucketed = (unsigned int*)(ws + OFF_BUCK);
    int*   edata  = (int*)(ws + OFF_EDATA);
    ushort* wthi  = (ushort*)(ws + OFF_WTHI);
    ushort* wtlo  = (ushort*)(ws + OFF_WTLO);
    int*   bhist  = (int*)(ws + OFF_BHIST);

    const int nchb = (ne + CHUNK - 1) / CHUNK;   // 391

    k_wsplit<<<(HID * KPAD + 255) / 256, 256, 0, stream>>>(W1, wthi, wtlo, gcnt);
    k_bcount<<<nchb, 256, 0, stream>>>(dst, gcnt, bhist, ne);
    k_bscan<<<1, 512, 0, stream>>>(gcnt, gbase, gcur, ne);
    k_bfill<<<nchb, 256, 0, stream>>>(src, dst, gcur, bhist, bucketed, ne);
    k_fine<<<NBUCK, 256, 0, stream>>>(gbase, bucketed, edata, rowptr, dinv, n, ne);
    k_gemm1<<<(n + 63) / 64, 256, 0, stream>>>(x, wthi, wtlo, h1, n);
    const int half = (n + 1) / 2;
    k_agg_fused<<<(half * 64 + 255) / 256, 256, 0, stream>>>(rowptr, edata, h1, dinv, b1, W2, z, 0, half);
    k_agg_fused<<<((n - half) * 64 + 255) / 256, 256, 0, stream>>>(rowptr, edata, h1, dinv, b1, W2, z, half, n - half);
    k_out<<<(n * 16 + 255) / 256, 256, 0, stream>>>(rowptr, edata, z, dinv, b2, out, n);
}

// Round 13
// 261.049 us; speedup vs baseline: 1.2479x; 1.0317x over previous
//
#include <hip/hip_runtime.h>

#define NN  100000
#define FIN 165
#define HID 128
#define NBUCK 391        // ceil(NN/256), bucket = dst >> 8
#define CHUNK 8192       // edges per block in bucket passes (write-locality sweet spot)
#define KPAD 192         // FIN padded to 6 k-steps of 32
#define BH_STRIDE 400    // per-block histogram row stride
#define XS 36            // LDS row stride in ushorts (18 dwords -> conflict-free)

typedef __attribute__((ext_vector_type(4))) float f32x4;
typedef __attribute__((ext_vector_type(8))) short short8;

// ws layout (4-byte units). h1 packed uint = bf16 pair (ch, ch+64) per node.
#define OFF_DINV   0
#define OFF_H1     100352
#define OFF_Z      (OFF_H1 + NN * 64)
#define OFF_ROWPTR (OFF_Z + 2 * NN)
#define OFF_GCNT   (OFF_ROWPTR + 100352)
#define OFF_GBASE  (OFF_GCNT + 512)
#define OFF_GCUR   (OFF_GBASE + 512)
#define OFF_BUCK   (OFF_GCUR + 512)
#define OFF_EDATA  (OFF_BUCK + 3200000)
#define OFF_WTHI   (OFF_EDATA + 3200000)          // 128*KPAD ushorts = 12288 uints
#define OFF_BHIST  (OFF_WTHI + 12288)             // nchb(391) * BH_STRIDE ints
// end ~= 13.5M * 4B ~= 54 MB

__device__ __forceinline__ unsigned bf16rne(float f) {
    unsigned u = __float_as_uint(f);
    return (u + 0x7FFFu + ((u >> 16) & 1u)) >> 16;
}

__device__ __forceinline__ float2 bf2_to_f2(unsigned int u) {
    float2 r;
    r.x = __uint_as_float(u << 16);
    r.y = __uint_as_float(u & 0xffff0000u);
    return r;
}

__device__ __forceinline__ short8 ldfrag(const ushort* p) {
    union { uint2 u[2]; short8 s; } f;
    f.u[0] = *(const uint2*)p;          // k = 4g .. 4g+3
    f.u[1] = *(const uint2*)(p + 16);   // k = 16+4g .. 16+4g+3
    return f.s;
}

// W1 -> bf16 (single RNE round), transposed to [ch][k], K zero-padded to KPAD.
// Also zeroes gcnt (folded k_zero).
__global__ void k_wsplit(const float* __restrict__ W1, ushort* __restrict__ hi,
                         int* __restrict__ gcnt) {
    int t = blockIdx.x * blockDim.x + threadIdx.x;
    if (t < 512) gcnt[t] = 0;
    if (t >= HID * KPAD) return;
    int ch = t / KPAD, k = t % KPAD;
    float v = (k < FIN) ? W1[k * HID + ch] : 0.0f;
    hi[ch * KPAD + k] = (ushort)bf16rne(v);
}

// coarse histogram by dst>>8 (int4 loads); persists per-block hist for k_bfill
__global__ __launch_bounds__(256) void k_bcount(const int* __restrict__ dst,
        int* __restrict__ gcnt, int* __restrict__ bhist, int ne) {
    __shared__ int hist[NBUCK];
    for (int i = threadIdx.x; i < NBUCK; i += 256) hist[i] = 0;
    __syncthreads();
    const int4* dst4 = (const int4*)dst;
    const int ne4 = ne >> 2;
    const int base4 = blockIdx.x * (CHUNK / 4);
#pragma unroll
    for (int it = 0; it < CHUNK / 1024; ++it) {
        int e4 = base4 + it * 256 + threadIdx.x;
        if (e4 < ne4) {
            int4 v = dst4[e4];
            atomicAdd(&hist[v.x >> 8], 1);
            atomicAdd(&hist[v.y >> 8], 1);
            atomicAdd(&hist[v.z >> 8], 1);
            atomicAdd(&hist[v.w >> 8], 1);
        }
    }
    if (blockIdx.x == 0 && threadIdx.x < (ne & 3))
        atomicAdd(&hist[dst[(ne & ~3) + threadIdx.x] >> 8], 1);
    __syncthreads();
    int* brow = bhist + (size_t)blockIdx.x * BH_STRIDE;
    for (int i = threadIdx.x; i < NBUCK; i += 256) {
        int h = hist[i];
        brow[i] = h;
        if (h) atomicAdd(&gcnt[i], h);
    }
}

__global__ __launch_bounds__(512) void k_bscan(const int* __restrict__ gcnt,
        int* __restrict__ gbase, int* __restrict__ gcur, int ne) {
    __shared__ int s[512];
    int tid = threadIdx.x;
    int v = (tid < NBUCK) ? gcnt[tid] : 0;
    s[tid] = v;
    __syncthreads();
    for (int off = 1; off < 512; off <<= 1) {
        int t = (tid >= off) ? s[tid - off] : 0;
        __syncthreads();
        s[tid] += t;
        __syncthreads();
    }
    if (tid < NBUCK) {
        int ex = s[tid] - v;
        gbase[tid] = ex;
        gcur[tid] = ex;
    }
    if (tid == 0) gbase[NBUCK] = ne;
}

// bucket fill: reuses k_bcount's histogram; int4 loads of src/dst
__global__ __launch_bounds__(256) void k_bfill(const int* __restrict__ src,
        const int* __restrict__ dst, int* __restrict__ gcur,
        const int* __restrict__ bhist, unsigned int* __restrict__ bucketed, int ne) {
    __shared__ int lcur[NBUCK];
    const int* brow = bhist + (size_t)blockIdx.x * BH_STRIDE;
    for (int i = threadIdx.x; i < NBUCK; i += 256) {
        int h = brow[i];
        lcur[i] = h ? atomicAdd(&gcur[i], h) : 0;
    }
    __syncthreads();
    const int4* dst4 = (const int4*)dst;
    const int4* src4 = (const int4*)src;
    const int ne4 = ne >> 2;
    const int base4 = blockIdx.x * (CHUNK / 4);
#pragma unroll
    for (int it = 0; it < CHUNK / 1024; ++it) {
        int e4 = base4 + it * 256 + threadIdx.x;
        if (e4 < ne4) {
            int4 d4 = dst4[e4];
            int4 s4 = src4[e4];
            int pos;
            pos = atomicAdd(&lcur[d4.x >> 8], 1);
            bucketed[pos] = (unsigned)s4.x | ((unsigned)(d4.x & 255) << 24);
            pos = atomicAdd(&lcur[d4.y >> 8], 1);
            bucketed[pos] = (unsigned)s4.y | ((unsigned)(d4.y & 255) << 24);
            pos = atomicAdd(&lcur[d4.z >> 8], 1);
            bucketed[pos] = (unsigned)s4.z | ((unsigned)(d4.z & 255) << 24);
            pos = atomicAdd(&lcur[d4.w >> 8], 1);
            bucketed[pos] = (unsigned)s4.w | ((unsigned)(d4.w & 255) << 24);
        }
    }
    if (blockIdx.x == 0 && threadIdx.x < (ne & 3)) {
        int e = (ne & ~3) + threadIdx.x;
        int d = dst[e];
        int pos = atomicAdd(&lcur[d >> 8], 1);
        bucketed[pos] = (unsigned)src[e] | ((unsigned)(d & 255) << 24);
    }
}

__global__ __launch_bounds__(256) void k_fine(const int* __restrict__ gbase,
        const unsigned int* __restrict__ bucketed, int* __restrict__ edata,
        int* __restrict__ rowptr, float* __restrict__ dinv, int n, int ne) {
    __shared__ int hist[256];
    __shared__ int scan[256];
    __shared__ int lcur[256];
    const int b = blockIdx.x;
    const int tid = threadIdx.x;
    const int beg = gbase[b], end = gbase[b + 1];
    hist[tid] = 0;
    __syncthreads();
    for (int j = beg + tid; j < end; j += 256)
        atomicAdd(&hist[bucketed[j] >> 24], 1);
    __syncthreads();
    int c = hist[tid];
    scan[tid] = c;
    __syncthreads();
    for (int off = 1; off < 256; off <<= 1) {
        int t = (tid >= off) ? scan[tid - off] : 0;
        __syncthreads();
        scan[tid] += t;
        __syncthreads();
    }
    int excl = scan[tid] - c;
    int d = b * 256 + tid;
    if (d < n) {
        rowptr[d] = beg + excl;
        dinv[d] = rsqrtf((float)c + 1.0f);   // +1 self-loop
    }
    lcur[tid] = beg + excl;
    __syncthreads();
    for (int j = beg + tid; j < end; j += 256) {
        unsigned p = bucketed[j];
        int pos = atomicAdd(&lcur[p >> 24], 1);
        edata[pos] = (int)(p & 0x00FFFFFFu);
    }
    if (b == NBUCK - 1 && tid == 0) rowptr[n] = ne;
}

// h1 = x @ W1 via MFMA: x AND W plain bf16 (single round each; x proven R9).
// LDS stride 36 ushorts = 18 dwords -> bank-conflict-free ds_read_b64
// (18*r15 mod 32 distinct for r15 in [0,16)). 64 nodes/block, 13.8 KB LDS.
// h1 packed: uint [node][u] = bf16(ch=u) | bf16(ch=u+64)<<16.
__global__ __launch_bounds__(256) void k_gemm1(const float* __restrict__ x,
        const ushort* __restrict__ wthi, unsigned* __restrict__ h1, int n) {
    __shared__ alignas(16) ushort xhi[64 * XS];
    __shared__ alignas(16) ushort whi[128 * XS];
    const int tid = threadIdx.x;
    const int node0 = blockIdx.x * 64;
    const int wv = tid >> 6, lane = tid & 63;
    const int r15 = lane & 15, g = lane >> 4;
    f32x4 acc[8];
#pragma unroll
    for (int ct = 0; ct < 8; ++ct) acc[ct] = (f32x4){0.f, 0.f, 0.f, 0.f};

    const int snd = tid >> 2, sq = tid & 3;     // x staging: 4 threads/node, 8 k each
    const int sch = tid >> 1, sh = tid & 1;     // W staging: 2 threads/ch, 16 k each

    for (int ks = 0; ks < 6; ++ks) {
        // stage W k-tile (bf16 hi only), rows at 72B stride (8B-aligned writes)
        {
            int gidx = sch * KPAD + ks * 32 + sh * 16;
            int lidx = sch * XS + sh * 16;
            uint4 a = *(const uint4*)&wthi[gidx];
            uint4 b = *(const uint4*)&wthi[gidx + 8];
            *(uint2*)&whi[lidx]      = make_uint2(a.x, a.y);
            *(uint2*)&whi[lidx + 4]  = make_uint2(a.z, a.w);
            *(uint2*)&whi[lidx + 8]  = make_uint2(b.x, b.y);
            *(uint2*)&whi[lidx + 12] = make_uint2(b.z, b.w);
        }
        // stage x k-tile: single bf16 round in flight
        {
            int node = node0 + snd;
            unsigned h8[8];
#pragma unroll
            for (int j = 0; j < 8; ++j) {
                int kk = ks * 32 + sq * 8 + j;
                float v = (node < n && kk < FIN) ? x[node * FIN + kk] : 0.0f;
                h8[j] = bf16rne(v);
            }
            int lidx = snd * XS + sq * 8;
            *(uint2*)&xhi[lidx]     = make_uint2(h8[0] | (h8[1] << 16), h8[2] | (h8[3] << 16));
            *(uint2*)&xhi[lidx + 4] = make_uint2(h8[4] | (h8[5] << 16), h8[6] | (h8[7] << 16));
        }
        __syncthreads();
        short8 Ah = ldfrag(&xhi[(wv * 16 + r15) * XS + 4 * g]);
#pragma unroll
        for (int ct = 0; ct < 8; ++ct) {
            short8 Bh = ldfrag(&whi[(ct * 16 + r15) * XS + 4 * g]);
            acc[ct] = __builtin_amdgcn_mfma_f32_16x16x32_bf16(Ah, Bh, acc[ct], 0, 0, 0);
        }
        __syncthreads();
    }
    // epilogue: C/D row = 4g + r, col = r15; pack (ct, ct+4) -> (ch, ch+64)
#pragma unroll
    for (int ct = 0; ct < 4; ++ct) {
#pragma unroll
        for (int r = 0; r < 4; ++r) {
            int node = node0 + wv * 16 + 4 * g + r;
            if (node < n) {
                unsigned p = bf16rne(acc[ct][r]) | (bf16rne(acc[ct + 4][r]) << 16);
                h1[node * 64 + ct * 16 + r15] = p;
            }
        }
    }
}

// one wave per dst node; 16 edges per iteration (4 per 16-lane group), with
// software-pipelined (src, norm) prefetch. L2-miss-BW bound (~3.3 TB/s).
// Processes nodes [n0, n0+nn) — launched twice for rocprof visibility.
__global__ __launch_bounds__(256) void k_agg_fused(const int* __restrict__ rowptr,
        const int* __restrict__ edata, const unsigned int* __restrict__ h1,
        const float* __restrict__ dinv, const float* __restrict__ b1,
        const float* __restrict__ W2, float* __restrict__ z, int n0, int nn) {
    const int wid  = (blockIdx.x * blockDim.x + threadIdx.x) >> 6;
    const int lane = threadIdx.x & 63;
    if (wid >= nn) return;
    const int d = n0 + wid;
    const int beg = rowptr[d], end = rowptr[d + 1];
    const float di = dinv[d];
    const int grp = lane >> 4;          // which edge slot of the 4-pack
    const int sl  = lane & 15;          // channel slice: uints sl*4..sl*4+3

    float ax0, ax1, ax2, ax3, ay0, ay1, ay2, ay3;
    {   // self-loop (group 0 only, weight di^2)
        uint4 hv = *(const uint4*)&h1[d * 64 + sl * 4];
        float nm = (grp == 0) ? di * di : 0.0f;
        float2 f0 = bf2_to_f2(hv.x), f1 = bf2_to_f2(hv.y);
        float2 f2 = bf2_to_f2(hv.z), f3 = bf2_to_f2(hv.w);
        ax0 = f0.x * nm; ay0 = f0.y * nm;
        ax1 = f1.x * nm; ay1 = f1.y * nm;
        ax2 = f2.x * nm; ay2 = f2.y * nm;
        ax3 = f3.x * nm; ay3 = f3.y * nm;
    }

#define PRELOAD(JB)                                                          \
    {                                                                        \
        int i0 = (JB) + grp, i1 = (JB) + 4 + grp,                            \
            i2 = (JB) + 8 + grp, i3 = (JB) + 12 + grp;                       \
        int c0 = min(i0, end - 1), c1 = min(i1, end - 1);                    \
        int c2 = min(i2, end - 1), c3 = min(i3, end - 1);                    \
        s0 = edata[c0]; s1 = edata[c1]; s2 = edata[c2]; s3 = edata[c3];      \
        m0 = (i0 < end) ? dinv[s0] * di : 0.0f;                              \
        m1 = (i1 < end) ? dinv[s1] * di : 0.0f;                              \
        m2 = (i2 < end) ? dinv[s2] * di : 0.0f;                              \
        m3 = (i3 < end) ? dinv[s3] * di : 0.0f;                              \
    }
#define ACC(G, NM)                                                           \
    {                                                                        \
        float2 f;                                                            \
        f = bf2_to_f2((G).x); ax0 = fmaf(f.x, (NM), ax0); ay0 = fmaf(f.y, (NM), ay0); \
        f = bf2_to_f2((G).y); ax1 = fmaf(f.x, (NM), ax1); ay1 = fmaf(f.y, (NM), ay1); \
        f = bf2_to_f2((G).z); ax2 = fmaf(f.x, (NM), ax2); ay2 = fmaf(f.y, (NM), ay2); \
        f = bf2_to_f2((G).w); ax3 = fmaf(f.x, (NM), ax3); ay3 = fmaf(f.y, (NM), ay3); \
    }

    if (beg < end) {
        int s0, s1, s2, s3;
        float m0, m1, m2, m3;
        PRELOAD(beg);
        for (int j = beg; j < end; j += 16) {
            uint4 g0 = *(const uint4*)&h1[s0 * 64 + sl * 4];
            uint4 g1 = *(const uint4*)&h1[s1 * 64 + sl * 4];
            uint4 g2 = *(const uint4*)&h1[s2 * 64 + sl * 4];
            uint4 g3 = *(const uint4*)&h1[s3 * 64 + sl * 4];
            float w0 = m0, w1 = m1, w2 = m2, w3 = m3;
            int jn = j + 16;
            if (jn < end) PRELOAD(jn);          // wave-uniform branch
            ACC(g0, w0); ACC(g1, w1); ACC(g2, w2); ACC(g3, w3);
        }
    }
#undef PRELOAD
#undef ACC

    ax0 += __shfl_xor(ax0, 16, 64); ax0 += __shfl_xor(ax0, 32, 64);
    ax1 += __shfl_xor(ax1, 16, 64); ax1 += __shfl_xor(ax1, 32, 64);
    ax2 += __shfl_xor(ax2, 16, 64); ax2 += __shfl_xor(ax2, 32, 64);
    ax3 += __shfl_xor(ax3, 16, 64); ax3 += __shfl_xor(ax3, 32, 64);
    ay0 += __shfl_xor(ay0, 16, 64); ay0 += __shfl_xor(ay0, 32, 64);
    ay1 += __shfl_xor(ay1, 16, 64); ay1 += __shfl_xor(ay1, 32, 64);
    ay2 += __shfl_xor(ay2, 16, 64); ay2 += __shfl_xor(ay2, 32, 64);
    ay3 += __shfl_xor(ay3, 16, 64); ay3 += __shfl_xor(ay3, 32, 64);
    // epilogue: channels c=sl*4+q (ax) and c+64 (ay); relu + W2 dot
    const int c = sl * 4;
    float4 bA = *(const float4*)&b1[c];
    float4 bB = *(const float4*)&b1[c + 64];
    float v00 = ax0 + bA.x; v00 = v00 > 0.f ? v00 : 0.f;
    float v01 = ax1 + bA.y; v01 = v01 > 0.f ? v01 : 0.f;
    float v02 = ax2 + bA.z; v02 = v02 > 0.f ? v02 : 0.f;
    float v03 = ax3 + bA.w; v03 = v03 > 0.f ? v03 : 0.f;
    float v10 = ay0 + bB.x; v10 = v10 > 0.f ? v10 : 0.f;
    float v11 = ay1 + bB.y; v11 = v11 > 0.f ? v11 : 0.f;
    float v12 = ay2 + bB.z; v12 = v12 > 0.f ? v12 : 0.f;
    float v13 = ay3 + bB.w; v13 = v13 > 0.f ? v13 : 0.f;
    float4 wA0 = *(const float4*)&W2[c * 2];
    float4 wA1 = *(const float4*)&W2[c * 2 + 4];
    float4 wB0 = *(const float4*)&W2[(c + 64) * 2];
    float4 wB1 = *(const float4*)&W2[(c + 64) * 2 + 4];
    float p0 = v00 * wA0.x + v01 * wA0.z + v02 * wA1.x + v03 * wA1.z
             + v10 * wB0.x + v11 * wB0.z + v12 * wB1.x + v13 * wB1.z;
    float p1 = v00 * wA0.y + v01 * wA0.w + v02 * wA1.y + v03 * wA1.w
             + v10 * wB0.y + v11 * wB0.w + v12 * wB1.y + v13 * wB1.w;
#pragma unroll
    for (int m = 8; m >= 1; m >>= 1) {
        p0 += __shfl_xor(p0, m, 64);
        p1 += __shfl_xor(p1, m, 64);
    }
    if (lane == 0) *(float2*)&z[d * 2] = make_float2(p0, p1);
}

// layer-2: 16-lane group per dst node, gather-side over the same CSR
__global__ __launch_bounds__(256) void k_out(const int* __restrict__ rowptr,
        const int* __restrict__ edata, const float* __restrict__ z,
        const float* __restrict__ dinv, const float* __restrict__ b2,
        float* __restrict__ out, int n) {
    int g = (blockIdx.x * blockDim.x + threadIdx.x) >> 4;
    int l = threadIdx.x & 15;
    if (g >= n) return;
    int beg = rowptr[g], end = rowptr[g + 1];
    float di = dinv[g];
    float o0 = 0.0f, o1 = 0.0f;
    for (int j = beg + l; j < end; j += 16) {
        int s = edata[j];
        float nm = dinv[s] * di;
        float2 zs = *(const float2*)&z[s * 2];
        o0 = fmaf(zs.x, nm, o0);
        o1 = fmaf(zs.y, nm, o1);
    }
#pragma unroll
    for (int m = 8; m >= 1; m >>= 1) {
        o0 += __shfl_xor(o0, m, 16);
        o1 += __shfl_xor(o1, m, 16);
    }
    if (l == 0) {
        float2 zd = *(const float2*)&z[g * 2];
        float s2 = di * di;
        out[g * 2]     = fmaf(zd.x, s2, b2[0]) + o0;
        out[g * 2 + 1] = fmaf(zd.y, s2, b2[1]) + o1;
    }
}

extern "C" void kernel_launch(void* const* d_in, const int* in_sizes, int n_in,
                              void* d_out, int out_size, void* d_ws, size_t ws_size,
                              hipStream_t stream) {
    const float* x  = (const float*)d_in[0];
    const int*   ei = (const int*)d_in[1];
    const float* W1 = (const float*)d_in[2];
    const float* b1 = (const float*)d_in[3];
    const float* W2 = (const float*)d_in[4];
    const float* b2 = (const float*)d_in[5];
    float* out = (float*)d_out;

    const int n  = in_sizes[0] / FIN;   // 100000
    const int ne = in_sizes[1] / 2;     // 3200000
    const int* src = ei;
    const int* dst = ei + ne;

    float* ws     = (float*)d_ws;
    float* dinv   = ws + OFF_DINV;
    unsigned int* h1 = (unsigned int*)(ws + OFF_H1);
    float* z      = ws + OFF_Z;
    int*   rowptr = (int*)(ws + OFF_ROWPTR);
    int*   gcnt   = (int*)(ws + OFF_GCNT);
    int*   gbase  = (int*)(ws + OFF_GBASE);
    int*   gcur   = (int*)(ws + OFF_GCUR);
    unsigned int* bucketed = (unsigned int*)(ws + OFF_BUCK);
    int*   edata  = (int*)(ws + OFF_EDATA);
    ushort* wthi  = (ushort*)(ws + OFF_WTHI);
    int*   bhist  = (int*)(ws + OFF_BHIST);

    const int nchb = (ne + CHUNK - 1) / CHUNK;   // 391

    k_wsplit<<<(HID * KPAD + 255) / 256, 256, 0, stream>>>(W1, wthi, gcnt);
    k_bcount<<<nchb, 256, 0, stream>>>(dst, gcnt, bhist, ne);
    k_bscan<<<1, 512, 0, stream>>>(gcnt, gbase, gcur, ne);
    k_bfill<<<nchb, 256, 0, stream>>>(src, dst, gcur, bhist, bucketed, ne);
    k_fine<<<NBUCK, 256, 0, stream>>>(gbase, bucketed, edata, rowptr, dinv, n, ne);
    k_gemm1<<<(n + 63) / 64, 256, 0, stream>>>(x, wthi, h1, n);
    const int half = (n + 1) / 2;
    k_agg_fused<<<(half * 64 + 255) / 256, 256, 0, stream>>>(rowptr, edata, h1, dinv, b1, W2, z, 0, half);
    k_agg_fused<<<((n - half) * 64 + 255) / 256, 256, 0, stream>>>(rowptr, edata, h1, dinv, b1, W2, z, half, n - half);
    k_out<<<(n * 16 + 255) / 256, 256, 0, stream>>>(rowptr, edata, z, dinv, b2, out, n);
}